// Round 18
// baseline (54.910 us; speedup 1.0000x reference)
//
#include <hip/hip_runtime.h>
#include <hip/hip_fp16.h>

// NCC loss: two streaming passes + tiny reduce.
// K1 (ncc_hw): wave = (b,d,chunk); lanes = staggered w (56 outputs/wave).
//   Marches H (8 segs x 20 + 8 halo  [r14-verified: 1920 blocks keeps
//   occupancy ~70%; 32-long segs dropped it to 44% and cost +8us]) with a
//   5ch x 9 f32 ring + running sums, packs to half2, W 9-tap IN-WAVE on
//   packed fp16 (TAP9H), stores 10B/voxel: uint2 {(S0,S1),(S2,S3)} +
//   ushort {S4}.
// K2 (ncc_d): golden consumer: thread per (b,h,w) marches D (5 segs x 32
//   + 8 halo  [r17-verified: 1.25x halo amplification, faster despite
//   1000 blocks - load-dominated, not occupancy-bound]) with a packed
//   9-slot ring (27 regs), dwordx2 + ushort loads, fp16 tree-sum, fp32
//   ncc, block reduce.
// K3: deterministic final reduction.

constexpr int BB = 2, DD = 160, HH = 160, WW = 160;
constexpr int SLICE = HH * WW;                         // 25600
constexpr long long NTOT = (long long)BB * DD * SLICE; // 8,192,000
constexpr int HSEG = 20, NHSEG = 8;                    // K1 h-segments (r14)
constexpr int DSEG = 32, NDSEG = 5;                    // K2 d-segments (r17)
constexpr int NPART = 200 * NDSEG;                     // 1000 partials

static __device__ __forceinline__ unsigned pkh(float a, float b) {
  __half2 h = __floats2half2_rn(a, b);
  return __builtin_bit_cast(unsigned, h);
}
static __device__ __forceinline__ __half2 h2(unsigned u) {
  return __builtin_bit_cast(__half2, u);
}

// 9-tap in-wave box sum on packed __half2 (both halves independently):
// v[l] <- sum_{k=0..8} v[l+k]   (valid for lane <= 55)
#define TAP9H(v)                                                         \
  {                                                                      \
    unsigned _u = __builtin_bit_cast(unsigned, v);                       \
    __half2 _t1 = __builtin_bit_cast(__half2, __shfl_down(_u, 1, 64));   \
    __half2 _t2 = __builtin_bit_cast(__half2, __shfl_down(_u, 2, 64));   \
    v = v + _t1 + _t2;                                                   \
    _u = __builtin_bit_cast(unsigned, v);                                \
    __half2 _t3 = __builtin_bit_cast(__half2, __shfl_down(_u, 3, 64));   \
    __half2 _t6 = __builtin_bit_cast(__half2, __shfl_down(_u, 6, 64));   \
    v = v + _t3 + _t6;                                                   \
  }

// ---------------- K1: H-ring + in-wave W-tap, 10B/voxel output ----------------
__global__ __launch_bounds__(256, 4) void ncc_hw_kernel(
    const float* __restrict__ f, const float* __restrict__ w,
    uint2* __restrict__ qA, ushort* __restrict__ qB) {
  const int tid = threadIdx.x;
  const int lane = tid & 63;
  const int wid = (blockIdx.x << 2) | (tid >> 6);  // 0..959 : (b,d,chunk)
  const int b = wid / 480;
  const int rem = wid % 480;
  const int d = rem / 3;
  const int ck = rem % 3;
  const int w_in = ck * 56 - 4 + lane;             // staggered input lane
  const int w_out = ck * 56 + lane;
  const bool vin = (unsigned)w_in < 160u;
  const bool vout = (lane < 56) && (w_out < 160);
  const int h0 = blockIdx.y * HSEG;
  const long long sb = (long long)(b * DD + d) * SLICE;
  const float* fr = f + sb + w_in;
  const float* wr = w + sb + w_in;

  float r0[9], r1[9], r2[9], r3[9], r4[9];
#pragma unroll
  for (int k = 0; k < 9; ++k) { r0[k] = r1[k] = r2[k] = r3[k] = r4[k] = 0.f; }
  float S0 = 0.f, S1 = 0.f, S2 = 0.f, S3 = 0.f, S4 = 0.f;

#pragma unroll
  for (int p = 0; p < HSEG + 8; ++p) {             // 28 steps
    const int j = h0 - 4 + p;                      // block-uniform guard
    float vf = 0.f, vw = 0.f;
    if ((unsigned)j < 160u && vin) {
      vf = fr[(long long)j * WW];
      vw = wr[(long long)j * WW];
    }
    const float a2 = vf * vf, a3 = vw * vw, a4 = vf * vw;
    const int sl = p % 9;                          // static after unroll
    S0 += vf - r0[sl]; r0[sl] = vf;
    S1 += vw - r1[sl]; r1[sl] = vw;
    S2 += a2 - r2[sl]; r2[sl] = a2;
    S3 += a3 - r3[sl]; r3[sl] = a3;
    S4 += a4 - r4[sl]; r4[sl] = a4;

    if (p >= 8) {
      __half2 z01 = h2(pkh(S0, S1));
      __half2 z23 = h2(pkh(S2, S3));
      __half2 z4x = h2(pkh(S4, 0.f));
      TAP9H(z01); TAP9H(z23); TAP9H(z4x);
      if (vout) {
        const long long rec = sb + (long long)(h0 + p - 8) * WW + w_out;
        qA[rec] = make_uint2(__builtin_bit_cast(unsigned, z01),
                             __builtin_bit_cast(unsigned, z23));
        qB[rec] = (ushort)(__builtin_bit_cast(unsigned, z4x) & 0xFFFFu);
      }
    }
  }
}

// ---------------- K2: golden D-march consumer: packed ring + tree + ncc ----------------
__global__ __launch_bounds__(256, 4) void ncc_d_kernel(
    const uint2* __restrict__ qA, const ushort* __restrict__ qB,
    float* __restrict__ partials) {
  const int tid = threadIdx.x;
  const int g = blockIdx.x * 256 + tid;            // 0..51199 : (b, h*W+w)
  const int b = g / SLICE;                         // blocks don't straddle b
  const int r = g % SLICE;
  const int d0 = blockIdx.y * DSEG;
  const long long base = (long long)b * DD * SLICE + r;

  // packed 9-slice ring: 27 regs, static slots after full unroll
  unsigned g0[9], g1[9], g2[9];
#pragma unroll
  for (int k = 0; k < 9; ++k) { g0[k] = 0u; g1[k] = 0u; g2[k] = 0u; }
  float acc = 0.f;
  const float inv = 1.0f / 729.0f;

#pragma unroll
  for (int p = 0; p < DSEG + 8; ++p) {             // 40 steps
    const int j = d0 - 4 + p;                      // block-uniform guard
    unsigned u0 = 0u, u1 = 0u, u2v = 0u;
    if ((unsigned)j < 160u) {
      const long long i = base + (long long)j * SLICE;
      const uint2 uu = qA[i];                      // dwordx2
      u0 = uu.x; u1 = uu.y;
      u2v = (unsigned)qB[i];                       // zero-extended: hi = +0.0
    }
    const int sl = p % 9;                          // static after unroll
    g0[sl] = u0; g1[sl] = u1; g2[sl] = u2v;

    if (p >= 8) {
      // D-window = sum of ALL 9 ring slots (order-free), packed fp16 tree
      __half2 z01 = ((h2(g0[0]) + h2(g0[1])) + (h2(g0[2]) + h2(g0[3]))) +
                    ((h2(g0[4]) + h2(g0[5])) + (h2(g0[6]) + h2(g0[7]))) +
                    h2(g0[8]);
      __half2 z23 = ((h2(g1[0]) + h2(g1[1])) + (h2(g1[2]) + h2(g1[3]))) +
                    ((h2(g1[4]) + h2(g1[5])) + (h2(g1[6]) + h2(g1[7]))) +
                    h2(g1[8]);
      __half2 z4x = ((h2(g2[0]) + h2(g2[1])) + (h2(g2[2]) + h2(g2[3]))) +
                    ((h2(g2[4]) + h2(g2[5])) + (h2(g2[6]) + h2(g2[7]))) +
                    h2(g2[8]);
      const float2 a01 = __half22float2(z01);
      const float2 a23 = __half22float2(z23);
      const float a4v = __half2float(__low2half(z4x));
      const float fm = a01.x * inv, wm = a01.y * inv;
      const float fv = a23.x * inv - fm * fm;
      const float wv = a23.y * inv - wm * wm;
      const float cov = a4v * inv - fm * wm;
      const float den2 = (fmaxf(fv, 0.f) + 1e-8f) * (fmaxf(wv, 0.f) + 1e-8f);
      const float ncc = cov * rsqrtf(den2);
      acc += fminf(1.f, fmaxf(-1.f, ncc));
    }
  }

  __shared__ float red[256];
  red[tid] = acc;
  __syncthreads();
#pragma unroll
  for (int st = 128; st > 0; st >>= 1) {
    if (tid < st) red[tid] += red[tid + st];
    __syncthreads();
  }
  if (tid == 0) partials[blockIdx.y * gridDim.x + blockIdx.x] = red[0];
}

// ---------------- K3: final reduction ----------------
__global__ __launch_bounds__(1024) void ncc_final_kernel(
    const float* __restrict__ partials, float* __restrict__ out) {
  const int t = threadIdx.x;
  float a = 0.f;
  for (int i = t; i < NPART; i += 1024) a += partials[i];
#pragma unroll
  for (int off = 32; off > 0; off >>= 1) a += __shfl_down(a, off, 64);
  __shared__ float wr[16];
  if ((t & 63) == 0) wr[t >> 6] = a;
  __syncthreads();
  if (t == 0) {
    float s = 0.f;
#pragma unroll
    for (int k = 0; k < 16; ++k) s += wr[k];
    out[0] = -s * (1.0f / (float)NTOT);
  }
}

extern "C" void kernel_launch(void* const* d_in, const int* in_sizes, int n_in,
                              void* d_out, int out_size, void* d_ws, size_t ws_size,
                              hipStream_t stream) {
  const float* fixed = (const float*)d_in[0];
  const float* warped = (const float*)d_in[1];
  float* out = (float*)d_out;

  uint2* qA = (uint2*)d_ws;                                      // 65.54 MB
  ushort* qB = (ushort*)((char*)d_ws + (size_t)NTOT * 8);        // 16.38 MB
  float* partials = (float*)((char*)d_ws + (size_t)NTOT * 10);   // 4.0 KB

  dim3 g1(240, NHSEG);            // 960 waves x 8 h-segs = 1920 blocks
  ncc_hw_kernel<<<g1, dim3(256), 0, stream>>>(fixed, warped, qA, qB);

  dim3 g2(200, NDSEG);            // 1000 blocks x 256
  ncc_d_kernel<<<g2, dim3(256), 0, stream>>>(qA, qB, partials);

  ncc_final_kernel<<<1, dim3(1024), 0, stream>>>(partials, out);
}

// Round 19
// 52.677 us; speedup vs baseline: 1.0424x; 1.0424x over previous
//
#include <hip/hip_runtime.h>
#include <hip/hip_fp16.h>

// NCC loss: two streaming passes + tiny reduce.  [r14 verified-best: 52.6us]
// K1 (ncc_hw): wave = (b,d,chunk); lanes = staggered w (56 outputs/wave).
//   Marches H (8 segs x 20 + 8 halo) with a 5ch x 9 f32 ring + running
//   window sums, packs to half2 and does the W 9-tap IN-WAVE on packed
//   fp16 (TAP9H), storing 10B/voxel: uint2 plane {(S0,S1),(S2,S3)} +
//   ushort plane {S4}.
// K2 (ncc_d): golden consumer: thread per (b,h,w) marches D (8 segs x 20
//   + 8) with a packed 9-slot ring (27 regs) fed by one dwordx2 + one
//   ushort load per step; D-window = fp16 tree-sum of the 9 slots; fp32
//   ncc; block reduce.
// K3: deterministic final reduction.
// Session-verified dead ends: full fusion (barrier-bound, r4), 2D LDS tiles
// (latency-starved, r3/r5), 2 voxels/thread (reg pressure, r15), last-block
// finalize (codegen blowup, r16), longer segments (occupancy, r17/r18),
// sw prefetch (null, r8), f32 rings in consumer (allocator remat, r10-12).

constexpr int BB = 2, DD = 160, HH = 160, WW = 160;
constexpr int SLICE = HH * WW;                         // 25600
constexpr long long NTOT = (long long)BB * DD * SLICE; // 8,192,000
constexpr int HSEG = 20, NHSEG = 8;                    // K1 h-segments
constexpr int DSEG = 20, NDSEG = 8;                    // K2 d-segments
constexpr int NPART = 200 * NDSEG;                     // 1600 partials

static __device__ __forceinline__ unsigned pkh(float a, float b) {
  __half2 h = __floats2half2_rn(a, b);
  return __builtin_bit_cast(unsigned, h);
}
static __device__ __forceinline__ __half2 h2(unsigned u) {
  return __builtin_bit_cast(__half2, u);
}

// 9-tap in-wave box sum on packed __half2 (both halves independently):
// v[l] <- sum_{k=0..8} v[l+k]   (valid for lane <= 55)
#define TAP9H(v)                                                         \
  {                                                                      \
    unsigned _u = __builtin_bit_cast(unsigned, v);                       \
    __half2 _t1 = __builtin_bit_cast(__half2, __shfl_down(_u, 1, 64));   \
    __half2 _t2 = __builtin_bit_cast(__half2, __shfl_down(_u, 2, 64));   \
    v = v + _t1 + _t2;                                                   \
    _u = __builtin_bit_cast(unsigned, v);                                \
    __half2 _t3 = __builtin_bit_cast(__half2, __shfl_down(_u, 3, 64));   \
    __half2 _t6 = __builtin_bit_cast(__half2, __shfl_down(_u, 6, 64));   \
    v = v + _t3 + _t6;                                                   \
  }

// ---------------- K1: H-ring + in-wave W-tap, 10B/voxel output ----------------
__global__ __launch_bounds__(256, 4) void ncc_hw_kernel(
    const float* __restrict__ f, const float* __restrict__ w,
    uint2* __restrict__ qA, ushort* __restrict__ qB) {
  const int tid = threadIdx.x;
  const int lane = tid & 63;
  const int wid = (blockIdx.x << 2) | (tid >> 6);  // 0..959 : (b,d,chunk)
  const int b = wid / 480;
  const int rem = wid % 480;
  const int d = rem / 3;
  const int ck = rem % 3;
  const int w_in = ck * 56 - 4 + lane;             // staggered input lane
  const int w_out = ck * 56 + lane;
  const bool vin = (unsigned)w_in < 160u;
  const bool vout = (lane < 56) && (w_out < 160);
  const int h0 = blockIdx.y * HSEG;
  const long long sb = (long long)(b * DD + d) * SLICE;
  const float* fr = f + sb + w_in;
  const float* wr = w + sb + w_in;

  float r0[9], r1[9], r2[9], r3[9], r4[9];
#pragma unroll
  for (int k = 0; k < 9; ++k) { r0[k] = r1[k] = r2[k] = r3[k] = r4[k] = 0.f; }
  float S0 = 0.f, S1 = 0.f, S2 = 0.f, S3 = 0.f, S4 = 0.f;

#pragma unroll
  for (int p = 0; p < HSEG + 8; ++p) {             // 28 steps
    const int j = h0 - 4 + p;                      // block-uniform guard
    float vf = 0.f, vw = 0.f;
    if ((unsigned)j < 160u && vin) {
      vf = fr[(long long)j * WW];
      vw = wr[(long long)j * WW];
    }
    const float a2 = vf * vf, a3 = vw * vw, a4 = vf * vw;
    const int sl = p % 9;                          // static after unroll
    S0 += vf - r0[sl]; r0[sl] = vf;
    S1 += vw - r1[sl]; r1[sl] = vw;
    S2 += a2 - r2[sl]; r2[sl] = a2;
    S3 += a3 - r3[sl]; r3[sl] = a3;
    S4 += a4 - r4[sl]; r4[sl] = a4;

    if (p >= 8) {
      __half2 z01 = h2(pkh(S0, S1));
      __half2 z23 = h2(pkh(S2, S3));
      __half2 z4x = h2(pkh(S4, 0.f));
      TAP9H(z01); TAP9H(z23); TAP9H(z4x);
      if (vout) {
        const long long rec = sb + (long long)(h0 + p - 8) * WW + w_out;
        qA[rec] = make_uint2(__builtin_bit_cast(unsigned, z01),
                             __builtin_bit_cast(unsigned, z23));
        qB[rec] = (ushort)(__builtin_bit_cast(unsigned, z4x) & 0xFFFFu);
      }
    }
  }
}

// ---------------- K2: golden D-march consumer: packed ring + tree + ncc ----------------
__global__ __launch_bounds__(256, 4) void ncc_d_kernel(
    const uint2* __restrict__ qA, const ushort* __restrict__ qB,
    float* __restrict__ partials) {
  const int tid = threadIdx.x;
  const int g = blockIdx.x * 256 + tid;            // 0..51199 : (b, h*W+w)
  const int b = g / SLICE;                         // blocks don't straddle b
  const int r = g % SLICE;
  const int d0 = blockIdx.y * DSEG;
  const long long base = (long long)b * DD * SLICE + r;

  // packed 9-slice ring: 27 regs, static slots after full unroll
  unsigned g0[9], g1[9], g2[9];
#pragma unroll
  for (int k = 0; k < 9; ++k) { g0[k] = 0u; g1[k] = 0u; g2[k] = 0u; }
  float acc = 0.f;
  const float inv = 1.0f / 729.0f;

#pragma unroll
  for (int p = 0; p < DSEG + 8; ++p) {             // 28 steps
    const int j = d0 - 4 + p;                      // block-uniform guard
    unsigned u0 = 0u, u1 = 0u, u2v = 0u;
    if ((unsigned)j < 160u) {
      const long long i = base + (long long)j * SLICE;
      const uint2 uu = qA[i];                      // dwordx2
      u0 = uu.x; u1 = uu.y;
      u2v = (unsigned)qB[i];                       // zero-extended: hi = +0.0
    }
    const int sl = p % 9;                          // static after unroll
    g0[sl] = u0; g1[sl] = u1; g2[sl] = u2v;

    if (p >= 8) {
      // D-window = sum of ALL 9 ring slots (order-free), packed fp16 tree
      __half2 z01 = ((h2(g0[0]) + h2(g0[1])) + (h2(g0[2]) + h2(g0[3]))) +
                    ((h2(g0[4]) + h2(g0[5])) + (h2(g0[6]) + h2(g0[7]))) +
                    h2(g0[8]);
      __half2 z23 = ((h2(g1[0]) + h2(g1[1])) + (h2(g1[2]) + h2(g1[3]))) +
                    ((h2(g1[4]) + h2(g1[5])) + (h2(g1[6]) + h2(g1[7]))) +
                    h2(g1[8]);
      __half2 z4x = ((h2(g2[0]) + h2(g2[1])) + (h2(g2[2]) + h2(g2[3]))) +
                    ((h2(g2[4]) + h2(g2[5])) + (h2(g2[6]) + h2(g2[7]))) +
                    h2(g2[8]);
      const float2 a01 = __half22float2(z01);
      const float2 a23 = __half22float2(z23);
      const float a4v = __half2float(__low2half(z4x));
      const float fm = a01.x * inv, wm = a01.y * inv;
      const float fv = a23.x * inv - fm * fm;
      const float wv = a23.y * inv - wm * wm;
      const float cov = a4v * inv - fm * wm;
      const float den2 = (fmaxf(fv, 0.f) + 1e-8f) * (fmaxf(wv, 0.f) + 1e-8f);
      const float ncc = cov * rsqrtf(den2);
      acc += fminf(1.f, fmaxf(-1.f, ncc));
    }
  }

  __shared__ float red[256];
  red[tid] = acc;
  __syncthreads();
#pragma unroll
  for (int st = 128; st > 0; st >>= 1) {
    if (tid < st) red[tid] += red[tid + st];
    __syncthreads();
  }
  if (tid == 0) partials[blockIdx.y * gridDim.x + blockIdx.x] = red[0];
}

// ---------------- K3: final reduction ----------------
__global__ __launch_bounds__(1024) void ncc_final_kernel(
    const float* __restrict__ partials, float* __restrict__ out) {
  const int t = threadIdx.x;
  float a = 0.f;
  for (int i = t; i < NPART; i += 1024) a += partials[i];
#pragma unroll
  for (int off = 32; off > 0; off >>= 1) a += __shfl_down(a, off, 64);
  __shared__ float wr[16];
  if ((t & 63) == 0) wr[t >> 6] = a;
  __syncthreads();
  if (t == 0) {
    float s = 0.f;
#pragma unroll
    for (int k = 0; k < 16; ++k) s += wr[k];
    out[0] = -s * (1.0f / (float)NTOT);
  }
}

extern "C" void kernel_launch(void* const* d_in, const int* in_sizes, int n_in,
                              void* d_out, int out_size, void* d_ws, size_t ws_size,
                              hipStream_t stream) {
  const float* fixed = (const float*)d_in[0];
  const float* warped = (const float*)d_in[1];
  float* out = (float*)d_out;

  uint2* qA = (uint2*)d_ws;                                      // 65.54 MB
  ushort* qB = (ushort*)((char*)d_ws + (size_t)NTOT * 8);        // 16.38 MB
  float* partials = (float*)((char*)d_ws + (size_t)NTOT * 10);   // 6.4 KB

  dim3 g1(240, NHSEG);            // 960 waves x 8 h-segs = 1920 blocks
  ncc_hw_kernel<<<g1, dim3(256), 0, stream>>>(fixed, warped, qA, qB);

  dim3 g2(200, NDSEG);            // 1600 blocks x 256
  ncc_d_kernel<<<g2, dim3(256), 0, stream>>>(qA, qB, partials);

  ncc_final_kernel<<<1, dim3(1024), 0, stream>>>(partials, out);
}